// Round 2
// baseline (1438.691 us; speedup 1.0000x reference)
//
#include <hip/hip_runtime.h>
#include <hip/hip_bf16.h>
#include <cmath>

#define T 2048
#define DIM 2048
#define QL 1536
#define NH 16
#define DH 256
#define HI 32
#define DI 128
#define SC 512
#define II 8192
#define NCOMB 1664   // 512 kv + 512 gate + 256 ikv + 256 igate + 32 iw, padded to 13*128

typedef __hip_bfloat16 bf16;
typedef __attribute__((ext_vector_type(8))) short bf16x8;
typedef __attribute__((ext_vector_type(4))) float f32x4;

#define DEVI static __device__ __forceinline__

DEVI float b2f(short u){ union{unsigned x; float f;} v; v.x = ((unsigned)(unsigned short)u)<<16u; return v.f; }
DEVI short f2b(float x){ union{ __hip_bfloat16 b; short s;} v; v.b = __float2bfloat16(x); return v.s; }
DEVI bf16 f2bf(float x){ return __float2bfloat16(x); }
DEVI float sigm(float x){ return 1.f / (1.f + __expf(-x)); }

DEVI void gload16(const void* g, void* l) {
  __builtin_amdgcn_global_load_lds((const __attribute__((address_space(1))) void*)g,
                                   (__attribute__((address_space(3))) void*)l, 16, 0, 0);
}

DEVI float blockReduceSum(float v) {
  __shared__ float red[4];
  int lane = threadIdx.x & 63, w = threadIdx.x >> 6;
  #pragma unroll
  for (int m = 32; m >= 1; m >>= 1) v += __shfl_xor(v, m, 64);
  if (lane == 0) red[w] = v;
  __syncthreads();
  int nw = blockDim.x >> 6;
  float s = 0.f;
  for (int i = 0; i < nw; i++) s += red[i];
  return s;
}

// ---------------- transpose f32(R,C) -> bf16(C,R) ----------------
__global__ void k_transpose(const float* __restrict__ in, bf16* __restrict__ out, int R, int C) {
  __shared__ float tile[32][33];
  int c0 = blockIdx.x * 32, r0 = blockIdx.y * 32;
  int tx = threadIdx.x, ty = threadIdx.y;   // block (32,8)
  #pragma unroll
  for (int i = 0; i < 4; i++)
    tile[ty + i*8][tx] = in[(size_t)(r0 + ty + i*8) * C + c0 + tx];
  __syncthreads();
  #pragma unroll
  for (int i = 0; i < 4; i++)
    out[(size_t)(c0 + ty + i*8) * R + r0 + tx] = f2bf(tile[tx][ty + i*8]);
}

// ---------------- plain convert f32 -> bf16 ----------------
__global__ void k_convert(const float* __restrict__ in, bf16* __restrict__ out, int n) {
  for (int i = blockIdx.x*256 + threadIdx.x; i < n; i += gridDim.x*256) out[i] = f2bf(in[i]);
}

// ---------------- row RMSNorm f32 -> bf16 ----------------
__global__ __launch_bounds__(256) void k_rms(const float* __restrict__ in, const float* __restrict__ w,
                                             bf16* __restrict__ out, int D) {
  int t = blockIdx.x;
  const float* row = in + (size_t)t * D;
  float ss = 0.f;
  for (int j = threadIdx.x; j < D/4; j += 256) {
    float4 v = ((const float4*)row)[j];
    ss += v.x*v.x + v.y*v.y + v.z*v.z + v.w*v.w;
  }
  ss = blockReduceSum(ss);
  float rs = rsqrtf(ss / (float)D + 1e-6f);
  for (int j = threadIdx.x; j < D/4; j += 256) {
    float4 v = ((const float4*)row)[j];
    float4 ww = ((const float4*)w)[j];
    union { short s[4]; uint2 u; } pk;
    pk.s[0] = f2b(v.x*rs*ww.x); pk.s[1] = f2b(v.y*rs*ww.y);
    pk.s[2] = f2b(v.z*rs*ww.z); pk.s[3] = f2b(v.w*rs*ww.w);
    ((uint2*)(out + (size_t)t*D))[j] = pk.u;
  }
}

// ---------------- rope tables: rows [0,T) from positions, rows [T,T+SC) pos=4s+3 ----------------
__global__ void k_rope_table(const int* __restrict__ positions, float* __restrict__ tabc, float* __restrict__ tabs) {
  int row = blockIdx.x * 8 + threadIdx.y;
  int i = threadIdx.x;   // 0..31
  if (row >= T + SC) return;
  float pos = (row < T) ? (float)positions[row] : (float)(4*(row - T) + 3);
  float freq = powf(160000.0f, -(float)i / 32.0f);
  float ang = pos * freq;
  tabc[(size_t)row*32 + i] = cosf(ang);
  tabs[(size_t)row*32 + i] = sinf(ang);
}

// ---------------- rope apply: f32 (T,Hn*Dn) -> bf16, rope dims >= nope ----------------
__global__ __launch_bounds__(256) void k_rope_apply(const float* __restrict__ in, bf16* __restrict__ out,
                                                    const float* __restrict__ tabc, const float* __restrict__ tabs,
                                                    int Hn, int Dn, int nope) {
  int t = blockIdx.x;
  int hd = blockIdx.y * 256 + threadIdx.x;
  int h = hd / Dn, d = hd - h*Dn;
  const float* row = in + (size_t)t * Hn * Dn;
  float val;
  if (d < nope) val = row[hd];
  else {
    int k = d - nope, i = k >> 1;
    float x0 = row[h*Dn + nope + 2*i], x1 = row[h*Dn + nope + 2*i + 1];
    float c = tabc[(size_t)t*32 + i], s = tabs[(size_t)t*32 + i];
    val = (k & 1) ? (x0*s + x1*c) : (x0*c - x1*s);
  }
  out[(size_t)t*Hn*Dn + hd] = f2bf(val);
}

// ---------------- generic bf16 GEMM: C(MxN) = A(MxK) * BT(NxK)^T, m97-style ----------------
template<int BF16_OUT, int RES>
__global__ __launch_bounds__(256) void k_gemm(
    const bf16* __restrict__ A, int lda, long long aZ,
    const bf16* __restrict__ BT, long long bZ,
    void* __restrict__ Cout, int ldc, int cZ,
    const float* __restrict__ resid, int K)
{
  __shared__ bf16 sA[128*32];
  __shared__ bf16 sB[128*32];
  const int tid = threadIdx.x;
  const int w = tid >> 6, lane = tid & 63;
  const int wr = w >> 1, wc = w & 1;
  const int kid = lane >> 4, lr = lane & 15;
  const int bm = blockIdx.y, bn = blockIdx.x, bz = blockIdx.z;
  const bf16* Ab = A + aZ*bz + (size_t)bm*128*lda;
  const bf16* Bb = BT + bZ*bz + (size_t)bn*128*K;
  f32x4 acc[4][4] = {};
  const int chb = w*128 + lane;
  for (int k0 = 0; k0 < K; k0 += 32) {
    #pragma unroll
    for (int i = 0; i < 2; i++) {
      int c = chb + i*64;
      gload16(Ab + (size_t)(c>>2)*lda + k0 + (c&3)*8, sA + (size_t)(w*128 + i*64)*8);
      gload16(Bb + (size_t)(c>>2)*K   + k0 + (c&3)*8, sB + (size_t)(w*128 + i*64)*8);
    }
    __syncthreads();
    bf16x8 a[4], b[4];
    #pragma unroll
    for (int m = 0; m < 4; m++) a[m] = *(const bf16x8*)(sA + (wr*64 + m*16 + lr)*32 + kid*8);
    #pragma unroll
    for (int n = 0; n < 4; n++) b[n] = *(const bf16x8*)(sB + (wc*64 + n*16 + lr)*32 + kid*8);
    #pragma unroll
    for (int m = 0; m < 4; m++)
      #pragma unroll
      for (int n = 0; n < 4; n++)
        acc[m][n] = __builtin_amdgcn_mfma_f32_16x16x32_bf16(a[m], b[n], acc[m][n], 0, 0, 0);
    __syncthreads();
  }
  const int rb = bm*128 + wr*64 + kid*4;
  const int cb = cZ*bz + bn*128 + wc*64 + lr;
  #pragma unroll
  for (int m = 0; m < 4; m++)
    #pragma unroll
    for (int n = 0; n < 4; n++)
      #pragma unroll
      for (int r = 0; r < 4; r++) {
        int row = rb + m*16 + r;
        int col = cb + n*16;
        float v = acc[m][n][r];
        if (RES) v += resid[(size_t)row*ldc + col];
        if (BF16_OUT) ((bf16*)Cout)[(size_t)row*ldc + col] = f2bf(v);
        else          ((float*)Cout)[(size_t)row*ldc + col] = v;
      }
}

// ---------------- indexer score GEMM + relu*iw reduction over 32 heads ----------------
__global__ __launch_bounds__(256) void k_iscore(
    const bf16* __restrict__ QI,   // (T*HI) x DI
    const bf16* __restrict__ KI,   // SC x DI
    const float* __restrict__ comb,// T x NCOMB (iw at col 1536)
    float* __restrict__ iscore)    // T x SC
{
  __shared__ bf16 sA[128*32];
  __shared__ bf16 sB[128*32];
  __shared__ float sc[512];
  const int tid = threadIdx.x;
  const int w = tid >> 6, lane = tid & 63;
  const int wr = w >> 1, wc = w & 1;
  const int kid = lane >> 4, lr = lane & 15;
  const int bm = blockIdx.y, bn = blockIdx.x;
  for (int i = tid; i < 512; i += 256) sc[i] = 0.f;
  const bf16* Ab = QI + (size_t)bm*128*DI;
  const bf16* Bb = KI + (size_t)bn*128*DI;
  f32x4 acc[4][4] = {};
  const int chb = w*128 + lane;
  for (int k0 = 0; k0 < DI; k0 += 32) {
    #pragma unroll
    for (int i = 0; i < 2; i++) {
      int c = chb + i*64;
      gload16(Ab + (size_t)(c>>2)*DI + k0 + (c&3)*8, sA + (size_t)(w*128 + i*64)*8);
      gload16(Bb + (size_t)(c>>2)*DI + k0 + (c&3)*8, sB + (size_t)(w*128 + i*64)*8);
    }
    __syncthreads();
    bf16x8 a[4], b[4];
    #pragma unroll
    for (int m = 0; m < 4; m++) a[m] = *(const bf16x8*)(sA + (wr*64 + m*16 + lr)*32 + kid*8);
    #pragma unroll
    for (int n = 0; n < 4; n++) b[n] = *(const bf16x8*)(sB + (wc*64 + n*16 + lr)*32 + kid*8);
    #pragma unroll
    for (int m = 0; m < 4; m++)
      #pragma unroll
      for (int n = 0; n < 4; n++)
        acc[m][n] = __builtin_amdgcn_mfma_f32_16x16x32_bf16(a[m], b[n], acc[m][n], 0, 0, 0);
    __syncthreads();
  }
  #pragma unroll
  for (int m = 0; m < 4; m++) {
    int rowl = wr*64 + m*16 + kid*4;
    #pragma unroll
    for (int r = 0; r < 4; r++) {
      int grow = bm*128 + rowl + r;
      int tt = grow >> 5, h = grow & 31;
      float wgt = comb[(size_t)tt*NCOMB + 1536 + h] * 0.08838834764831845f;  // * ISCALE
      #pragma unroll
      for (int n = 0; n < 4; n++) {
        float v = fmaxf(acc[m][n][r], 0.f) * wgt;
        atomicAdd(&sc[((rowl + r) >> 5)*128 + wc*64 + n*16 + lr], v);
      }
    }
  }
  __syncthreads();
  for (int i = tid; i < 512; i += 256)
    iscore[(size_t)(bm*4 + (i >> 7))*SC + bn*128 + (i & 127)] = sc[i];
}

// ---------------- compress combine (main kvc, d=256) ----------------
__global__ __launch_bounds__(256) void k_combine_c(
    const float* __restrict__ comb, const float* __restrict__ ape, const float* __restrict__ normw,
    const float* __restrict__ tabc, const float* __restrict__ tabs,
    bf16* __restrict__ kvc, bf16* __restrict__ kvcT)
{
  const int b = blockIdx.x, j = threadIdx.x;  // 256 threads
  float acc = 0.f;
  #pragma unroll
  for (int r = 0; r < 4; r++) {
    if (b > 0) {
      size_t tt = (size_t)(4*(b-1)+r) * NCOMB;
      acc += comb[tt + j] * sigm(comb[tt + 512 + j]) + ape[r*512 + j];
    }
    size_t t2 = (size_t)(4*b+r) * NCOMB;
    acc += comb[t2 + 256 + j] * sigm(comb[t2 + 512 + 256 + j]) + ape[r*512 + 256 + j];
  }
  acc *= 0.125f;
  float ss = blockReduceSum(acc*acc);
  float rs = rsqrtf(ss * (1.f/256.f) + 1e-6f);
  float nv = acc * rs * normw[j];
  __shared__ float sh[256];
  sh[j] = nv;
  __syncthreads();
  float outv;
  if (j < 192) outv = nv;
  else {
    int k = j - 192, i = k >> 1;
    float x0 = sh[192 + 2*i], x1 = sh[193 + 2*i];
    float c = tabc[(size_t)(T + b)*32 + i], sn = tabs[(size_t)(T + b)*32 + i];
    outv = (k & 1) ? (x0*sn + x1*c) : (x0*c - x1*sn);
  }
  kvc[(size_t)b*DH + j] = f2bf(outv);
  kvcT[(size_t)j*SC + b] = f2bf(outv);
}

// ---------------- compress combine (indexer ki, d=128) ----------------
__global__ __launch_bounds__(128) void k_combine_i(
    const float* __restrict__ comb, const float* __restrict__ ape, const float* __restrict__ normw,
    const float* __restrict__ tabc, const float* __restrict__ tabs,
    bf16* __restrict__ ki)
{
  const int b = blockIdx.x, j = threadIdx.x;  // 128 threads
  float acc = 0.f;
  #pragma unroll
  for (int r = 0; r < 4; r++) {
    if (b > 0) {
      size_t tt = (size_t)(4*(b-1)+r) * NCOMB;
      acc += comb[tt + 1024 + j] * sigm(comb[tt + 1280 + j]) + ape[r*256 + j];
    }
    size_t t2 = (size_t)(4*b+r) * NCOMB;
    acc += comb[t2 + 1024 + 128 + j] * sigm(comb[t2 + 1280 + 128 + j]) + ape[r*256 + 128 + j];
  }
  acc *= 0.125f;
  float ss = blockReduceSum(acc*acc);
  float rs = rsqrtf(ss * (1.f/128.f) + 1e-6f);
  float nv = acc * rs * normw[j];
  __shared__ float sh[128];
  sh[j] = nv;
  __syncthreads();
  float outv;
  if (j < 64) outv = nv;
  else {
    int k = j - 64, i = k >> 1;
    float x0 = sh[64 + 2*i], x1 = sh[64 + 2*i + 1];
    float c = tabc[(size_t)(T + b)*32 + i], sn = tabs[(size_t)(T + b)*32 + i];
    outv = (k & 1) ? (x0*sn + x1*c) : (x0*c - x1*sn);
  }
  ki[(size_t)b*DI + j] = f2bf(outv);
}

// ---------------- top-k threshold per row (bitonic sort 512 in LDS) ----------------
__global__ __launch_bounds__(256) void k_topk(const float* __restrict__ iscore,
                                              const int* __restrict__ positions,
                                              float* __restrict__ thresh) {
  const int t = blockIdx.x;
  int pos = positions[t];
  int nv = (pos + 1) >> 2; if (nv > SC) nv = SC;
  if (nv <= 256) { if (threadIdx.x == 0) thresh[t] = -3e38f; return; }
  __shared__ float arr[512];
  for (int i = threadIdx.x; i < 512; i += 256)
    arr[i] = (i < nv) ? iscore[(size_t)t*SC + i] : -1e30f;
  __syncthreads();
  for (int k = 2; k <= 512; k <<= 1)
    for (int j = k >> 1; j > 0; j >>= 1) {
      for (int idx = threadIdx.x; idx < 512; idx += 256) {
        int ixj = idx ^ j;
        if (ixj > idx) {
          bool up = ((idx & k) == 0);   // descending
          float a = arr[idx], b = arr[ixj];
          if (up ? (a < b) : (a > b)) { arr[idx] = b; arr[ixj] = a; }
        }
      }
      __syncthreads();
    }
  if (threadIdx.x == 0) thresh[t] = arr[255];
}

// ---------------- fused sparse attention: one block per token ----------------
__global__ __launch_bounds__(256) void k_attn(
    const bf16* __restrict__ q, const bf16* __restrict__ kvc, const bf16* __restrict__ kvcT,
    const float* __restrict__ iscore, const float* __restrict__ thresh,
    const int* __restrict__ positions, const float* __restrict__ sink,
    bf16* __restrict__ o)
{
  const int t = blockIdx.x;
  const int tid = threadIdx.x, w = tid >> 6, lane = tid & 63;
  const int kid = lane >> 4, lr = lane & 15;
  __shared__ bf16 pl[16*528];
  __shared__ float redm[4][16], reds[4][16];
  int pos = positions[t];
  int nv = (pos + 1) >> 2; if (nv > SC) nv = SC;
  float th = thresh[t];
  bf16x8 aq[8];
  const bf16* qrow = q + (size_t)t*(NH*DH) + lr*DH + kid*8;
  #pragma unroll
  for (int ks = 0; ks < 8; ks++) aq[ks] = *(const bf16x8*)(qrow + ks*32);
  f32x4 acc[8] = {};
  const int s0 = w*128;
  if (s0 < nv) {
    #pragma unroll
    for (int ks = 0; ks < 8; ks++) {
      bf16x8 bq[8];
      #pragma unroll
      for (int n = 0; n < 8; n++)
        bq[n] = *(const bf16x8*)(kvc + (size_t)(s0 + n*16 + lr)*DH + ks*32 + kid*8);
      #pragma unroll
      for (int n = 0; n < 8; n++)
        acc[n] = __builtin_amdgcn_mfma_f32_16x16x32_bf16(aq[ks], bq[n], acc[n], 0, 0, 0);
    }
  }
  float p[8][4];
  float mx[4] = {-3e38f, -3e38f, -3e38f, -3e38f};
  #pragma unroll
  for (int n = 0; n < 8; n++) {
    int s = s0 + n*16 + lr;
    bool keep = (s < nv) && (iscore[(size_t)t*SC + s] >= th);
    #pragma unroll
    for (int r = 0; r < 4; r++) {
      float v = keep ? acc[n][r] * 0.0625f : -1e30f;  // SCALE = DH^-0.5
      p[n][r] = v;
      mx[r] = fmaxf(mx[r], v);
    }
  }
  #pragma unroll
  for (int m2 = 1; m2 <= 8; m2 <<= 1)
    #pragma unroll
    for (int r = 0; r < 4; r++) mx[r] = fmaxf(mx[r], __shfl_xor(mx[r], m2, 64));
  if (lr == 0) {
    #pragma unroll
    for (int r = 0; r < 4; r++) redm[w][kid*4 + r] = mx[r];
  }
  __syncthreads();
  float M[4], sm[4];
  #pragma unroll
  for (int r = 0; r < 4; r++) {
    int h = kid*4 + r;
    float m = fmaxf(fmaxf(redm[0][h], redm[1][h]), fmaxf(redm[2][h], redm[3][h]));
    M[r] = fmaxf(m, sink[h]);
    sm[r] = 0.f;
  }
  #pragma unroll
  for (int n = 0; n < 8; n++)
    #pragma unroll
    for (int r = 0; r < 4; r++) {
      float e = __expf(p[n][r] - M[r]);
      p[n][r] = e;
      sm[r] += e;
    }
  #pragma unroll
  for (int m2 = 1; m2 <= 8; m2 <<= 1)
    #pragma unroll
    for (int r = 0; r < 4; r++) sm[r] += __shfl_xor(sm[r], m2, 64);
  if (lr == 0) {
    #pragma unroll
    for (int r = 0; r < 4; r++) reds[w][kid*4 + r] = sm[r];
  }
  __syncthreads();
  float inv[4];
  #pragma unroll
  for (int r = 0; r < 4; r++) {
    int h = kid*4 + r;
    float den = reds[0][h] + reds[1][h] + reds[2][h] + reds[3][h] + __expf(sink[h] - M[r]);
    inv[r] = 1.f / den;
  }
  #pragma unroll
  for (int n = 0; n < 8; n++)
    #pragma unroll
    for (int r = 0; r < 4; r++)
      pl[(kid*4 + r)*528 + s0 + n*16 + lr] = f2bf(p[n][r] * inv[r]);
  __syncthreads();
  int nch = (nv + 31) >> 5; if (nch > 16) nch = 16;
  f32x4 oacc[4] = {};
  for (int ks = 0; ks < nch; ks++) {
    bf16x8 ap = *(const bf16x8*)(pl + lr*528 + ks*32 + kid*8);
    #pragma unroll
    for (int n = 0; n < 4; n++) {
      bf16x8 bv = *(const bf16x8*)(kvcT + (size_t)(w*64 + n*16 + lr)*SC + ks*32 + kid*8);
      oacc[n] = __builtin_amdgcn_mfma_f32_16x16x32_bf16(ap, bv, oacc[n], 0, 0, 0);
    }
  }
  #pragma unroll
  for (int n = 0; n < 4; n++)
    #pragma unroll
    for (int r = 0; r < 4; r++)
      o[(size_t)t*(NH*DH) + (kid*4 + r)*DH + w*64 + n*16 + lr] = f2bf(oacc[n][r]);
}

// ---------------- SwiGLU activation ----------------
__global__ __launch_bounds__(256) void k_act(const bf16* __restrict__ gu, bf16* __restrict__ a) {
  size_t i = (size_t)blockIdx.x*256 + threadIdx.x;   // one 8-vector each
  size_t t = i >> 10;            // 1024 vectors per row (8192/8)
  size_t c = (i & 1023) * 8;
  bf16x8 g8 = *(const bf16x8*)(gu + t*16384 + c);
  bf16x8 u8 = *(const bf16x8*)(gu + t*16384 + 8192 + c);
  union { short s[8]; bf16x8 v; } outp;
  #pragma unroll
  for (int j = 0; j < 8; j++) {
    float g = b2f(g8[j]), u = b2f(u8[j]);
    outp.s[j] = f2b((g / (1.f + __expf(-g))) * u);
  }
  *(bf16x8*)(a + t*8192 + c) = outp.v;
}

extern "C" void kernel_launch(void* const* d_in, const int* in_sizes, int n_in,
                              void* d_out, int out_size, void* d_ws, size_t ws_size,
                              hipStream_t stream) {
  const float* hidden        = (const float*)d_in[0];
  const int*   positions     = (const int*)  d_in[1];
  const float* ln1_w         = (const float*)d_in[2];
  const float* ln2_w         = (const float*)d_in[3];
  const float* wq_a          = (const float*)d_in[4];
  const float* q_norm_w      = (const float*)d_in[5];
  const float* wq_b          = (const float*)d_in[6];
  const float* comp_wkv      = (const float*)d_in[7];
  const float* comp_wgate    = (const float*)d_in[8];
  const float* comp_ape      = (const float*)d_in[9];
  const float* comp_norm_w   = (const float*)d_in[10];
  const float* idx_wq_b      = (const float*)d_in[11];
  const float* idx_wproj     = (const float*)d_in[12];
  const float* icomp_wkv     = (const float*)d_in[13];
  const float* icomp_wgate   = (const float*)d_in[14];
  const float* icomp_ape     = (const float*)d_in[15];
  const float* icomp_norm_w  = (const float*)d_in[16];
  const float* attn_sink     = (const float*)d_in[17];
  const float* wo_a          = (const float*)d_in[18];
  const float* wo_b          = (const float*)d_in[19];
  const float* gate_up_w     = (const float*)d_in[20];
  const float* down_w        = (const float*)d_in[21];
  float* outp = (float*)d_out;

  char* p = (char*)d_ws;
  auto take = [&](size_t n) { char* r = p; p += (n + 255) & ~(size_t)255; return r; };
  // ---- persistent bf16 weights (~151 MB) ----
  bf16* wq_aT    = (bf16*)take((size_t)QL*DIM*2);        // 6.3 MB
  bf16* wq_bT    = (bf16*)take((size_t)4096*QL*2);       // 12.6 MB
  bf16* idx_wq_bT= (bf16*)take((size_t)4096*QL*2);       // 12.6 MB
  bf16* WcombT   = (bf16*)take((size_t)NCOMB*DIM*2);     // 6.8 MB
  bf16* wo_a_bf  = (bf16*)take((size_t)4*512*1024*2);    // 4.2 MB
  bf16* wo_bT    = (bf16*)take((size_t)DIM*DIM*2);       // 8.4 MB
  bf16* gate_upT = (bf16*)take((size_t)2*II*DIM*2);      // 67.1 MB
  bf16* downT    = (bf16*)take((size_t)DIM*II*2);        // 33.6 MB
  bf16* x_bf     = (bf16*)take((size_t)T*DIM*2);         // 8.4 MB
  // ---- R1 (64 MB): {qtmp f32 32MB | q_bf 16MB | qi_bf 16MB}
  //      then {o_bf 16MB | oa_bf 8MB | ...} (qtmp dead), then gu 64MB (all dead)
  char* R1 = take((size_t)T*16384*2);
  float* qtmp  = (float*)R1;
  bf16*  q_bf  = (bf16*)(R1 + (size_t)33554432);
  bf16*  qi_bf = (bf16*)(R1 + (size_t)50331648);
  bf16*  o_bf  = (bf16*)R1;
  bf16*  oa_bf = (bf16*)(R1 + (size_t)16777216);
  bf16*  gu    = (bf16*)R1;
  // ---- R2 (36.7 MB): {qx 12.6 | qr 6.3 | comb 13.6 | iscore 4.2}
  //      then x2 over comb (comb dead), then a_bf 33.6MB over all (all dead)
  char* R2 = take((size_t)36700160);
  float* qx     = (float*)R2;
  bf16*  qr     = (bf16*)(R2 + (size_t)12582912);
  float* comb   = (float*)(R2 + (size_t)18874368);
  float* iscore = (float*)(R2 + (size_t)32505856);
  bf16*  x2     = (bf16*)(R2 + (size_t)18874368);
  bf16*  a_bf   = (bf16*)R2;
  // ---- persistent small ----
  float* hbuf = (float*)take((size_t)T*DIM*4);           // 16.8 MB
  bf16* kvc   = (bf16*)take((size_t)SC*DH*2);
  bf16* kvcT  = (bf16*)take((size_t)DH*SC*2);
  bf16* ki    = (bf16*)take((size_t)SC*DI*2);
  float* tabc = (float*)take((size_t)(T+SC)*32*4);
  float* tabs = (float*)take((size_t)(T+SC)*32*4);
  float* thr  = (float*)take((size_t)T*4);

  dim3 tb(32, 8);
  // weight convert/transpose (f32 row-major -> bf16 transposed / B^T form)
  k_transpose<<<dim3(QL/32, DIM/32), tb, 0, stream>>>(wq_a, wq_aT, DIM, QL);
  k_transpose<<<dim3(4096/32, QL/32), tb, 0, stream>>>(wq_b, wq_bT, QL, 4096);
  k_transpose<<<dim3(4096/32, QL/32), tb, 0, stream>>>(idx_wq_b, idx_wq_bT, QL, 4096);
  k_transpose<<<dim3(512/32, DIM/32), tb, 0, stream>>>(comp_wkv,   WcombT + (size_t)0*DIM,    DIM, 512);
  k_transpose<<<dim3(512/32, DIM/32), tb, 0, stream>>>(comp_wgate, WcombT + (size_t)512*DIM,  DIM, 512);
  k_transpose<<<dim3(256/32, DIM/32), tb, 0, stream>>>(icomp_wkv,  WcombT + (size_t)1024*DIM, DIM, 256);
  k_transpose<<<dim3(256/32, DIM/32), tb, 0, stream>>>(icomp_wgate,WcombT + (size_t)1280*DIM, DIM, 256);
  k_transpose<<<dim3(32/32, DIM/32), tb, 0, stream>>>(idx_wproj,   WcombT + (size_t)1536*DIM, DIM, 32);
  k_transpose<<<dim3(DIM/32, DIM/32), tb, 0, stream>>>(wo_b, wo_bT, DIM, DIM);
  k_transpose<<<dim3(16384/32, DIM/32), tb, 0, stream>>>(gate_up_w, gate_upT, DIM, 16384);
  k_transpose<<<dim3(DIM/32, II/32), tb, 0, stream>>>(down_w, downT, II, DIM);
  k_convert<<<2048, 256, 0, stream>>>(wo_a, wo_a_bf, 4*512*1024);
  k_rope_table<<<(T + SC + 7)/8, tb, 0, stream>>>(positions, tabc, tabs);

  // x = rms(hidden, ln1)
  k_rms<<<T, 256, 0, stream>>>(hidden, ln1_w, x_bf, DIM);
  // qx = x @ wq_a ; qr = rms(qx, q_norm_w)
  k_gemm<0,0><<<dim3(QL/128, T/128), 256, 0, stream>>>(x_bf, DIM, 0, wq_aT, 0, qx, QL, 0, nullptr, DIM);
  k_rms<<<T, 256, 0, stream>>>(qx, q_norm_w, qr, QL);
  // q = rope(qr @ wq_b)
  k_gemm<0,0><<<dim3(4096/128, T/128), 256, 0, stream>>>(qr, QL, 0, wq_bT, 0, qtmp, 4096, 0, nullptr, QL);
  k_rope_apply<<<dim3(T, 16), 256, 0, stream>>>(qtmp, q_bf, tabc, tabs, NH, DH, 192);
  // qi = rope(qr @ idx_wq_b)
  k_gemm<0,0><<<dim3(4096/128, T/128), 256, 0, stream>>>(qr, QL, 0, idx_wq_bT, 0, qtmp, 4096, 0, nullptr, QL);
  k_rope_apply<<<dim3(T, 16), 256, 0, stream>>>(qtmp, qi_bf, tabc, tabs, HI, DI, 64);
  // comb = x @ [comp_wkv|comp_wgate|icomp_wkv|icomp_wgate|idx_proj]
  k_gemm<0,0><<<dim3(NCOMB/128, T/128), 256, 0, stream>>>(x_bf, DIM, 0, WcombT, 0, comb, NCOMB, 0, nullptr, DIM);
  k_combine_c<<<SC, 256, 0, stream>>>(comb, comp_ape, comp_norm_w, tabc, tabs, kvc, kvcT);
  k_combine_i<<<SC, 128, 0, stream>>>(comb, icomp_ape, icomp_norm_w, tabc, tabs, ki);
  // indexer scores + top-k threshold
  k_iscore<<<dim3(4, 512), 256, 0, stream>>>(qi_bf, ki, comb, iscore);
  k_topk<<<T, 256, 0, stream>>>(iscore, positions, thr);
  // sparse attention
  k_attn<<<T, 256, 0, stream>>>(q_bf, kvc, kvcT, iscore, thr, positions, attn_sink, o_bf);
  // oa = grouped o @ wo_a
  k_gemm<1,0><<<dim3(4, T/128, 4), 256, 0, stream>>>(o_bf, NH*DH, 1024, wo_a_bf, (long long)512*1024,
                                                     oa_bf, DIM, 512, nullptr, 1024);
  // h = hidden + oa @ wo_b
  k_gemm<0,1><<<dim3(DIM/128, T/128), 256, 0, stream>>>(oa_bf, DIM, 0, wo_bT, 0, hbuf, DIM, 0, hidden, DIM);
  k_rms<<<T, 256, 0, stream>>>(hbuf, ln2_w, x2, DIM);
  // MLP
  k_gemm<1,0><<<dim3(16384/128, T/128), 256, 0, stream>>>(x2, DIM, 0, gate_upT, 0, gu, 16384, 0, nullptr, DIM);
  k_act<<<(int)((size_t)T*II/8/256), 256, 0, stream>>>(gu, a_bf);
  k_gemm<0,1><<<dim3(DIM/128, T/128), 256, 0, stream>>>(a_bf, II, 0, downT, 0, outp, DIM, 0, hbuf, II);
}

// Round 5
// 1339.571 us; speedup vs baseline: 1.0740x; 1.0740x over previous
//
#include <hip/hip_runtime.h>
#include <hip/hip_bf16.h>
#include <cmath>

#define T 2048
#define DIM 2048
#define QL 1536
#define NH 16
#define DH 256
#define HI 32
#define DI 128
#define SC 512
#define II 8192
#define NCOMB 1664   // 512 kv + 512 gate + 256 ikv + 256 igate + 32 iw, padded to 13*128

typedef __hip_bfloat16 bf16;
typedef __attribute__((ext_vector_type(8))) short bf16x8;
typedef __attribute__((ext_vector_type(4))) float f32x4;

#define DEVI static __device__ __forceinline__

DEVI float b2f(short u){ union{unsigned x; float f;} v; v.x = ((unsigned)(unsigned short)u)<<16u; return v.f; }
DEVI short f2b(float x){ union{ __hip_bfloat16 b; short s;} v; v.b = __float2bfloat16(x); return v.s; }
DEVI bf16 f2bf(float x){ return __float2bfloat16(x); }
DEVI float sigm(float x){ return 1.f / (1.f + __expf(-x)); }

DEVI void gload16(const void* g, void* l) {
  __builtin_amdgcn_global_load_lds((const __attribute__((address_space(1))) void*)g,
                                   (__attribute__((address_space(3))) void*)l, 16, 0, 0);
}

DEVI float blockReduceSum(float v) {
  __shared__ float red[4];
  int lane = threadIdx.x & 63, w = threadIdx.x >> 6;
  #pragma unroll
  for (int m = 32; m >= 1; m >>= 1) v += __shfl_xor(v, m, 64);
  if (lane == 0) red[w] = v;
  __syncthreads();
  int nw = blockDim.x >> 6;
  float s = 0.f;
  for (int i = 0; i < nw; i++) s += red[i];
  return s;
}

// ---------------- transpose f32(R,C) -> bf16(C,R), 64x64 tile, vectorized ----------------
__global__ __launch_bounds__(256) void k_transpose64(const float* __restrict__ in, bf16* __restrict__ out,
                                                     int R, int C) {
  __shared__ float tile[64][65];
  int c0 = blockIdx.x * 64, r0 = blockIdx.y * 64;
  int tid = threadIdx.x;
  int cg = tid & 15, rr = tid >> 4;   // 16 float4 col-groups x 16 rows, 4 iters
  #pragma unroll
  for (int rb = 0; rb < 4; rb++) {
    int row = rb*16 + rr;
    float4 v = *(const float4*)(in + (size_t)(r0+row)*C + c0 + cg*4);
    tile[row][cg*4+0] = v.x; tile[row][cg*4+1] = v.y;
    tile[row][cg*4+2] = v.z; tile[row][cg*4+3] = v.w;
  }
  __syncthreads();
  int cc = tid >> 3, rblk = tid & 7;  // 32 out-rows x 8 bf16x8-blocks, 2 iters
  #pragma unroll
  for (int ci = 0; ci < 2; ci++) {
    int c = ci*32 + cc;
    union { short s[8]; bf16x8 v; } pk;
    #pragma unroll
    for (int i = 0; i < 8; i++) pk.s[i] = f2b(tile[rblk*8+i][c]);
    *(bf16x8*)(out + (size_t)(c0+c)*R + r0 + rblk*8) = pk.v;
  }
}

// ---------------- small transpose (for 32-col idx_wproj) ----------------
__global__ void k_transpose32(const float* __restrict__ in, bf16* __restrict__ out, int R, int C) {
  __shared__ float tile[32][33];
  int c0 = blockIdx.x * 32, r0 = blockIdx.y * 32;
  int tx = threadIdx.x, ty = threadIdx.y;   // block (32,8)
  #pragma unroll
  for (int i = 0; i < 4; i++)
    tile[ty + i*8][tx] = in[(size_t)(r0 + ty + i*8) * C + c0 + tx];
  __syncthreads();
  #pragma unroll
  for (int i = 0; i < 4; i++)
    out[(size_t)(c0 + ty + i*8) * R + r0 + tx] = f2bf(tile[tx][ty + i*8]);
}

// ---------------- plain convert f32 -> bf16 ----------------
__global__ void k_convert(const float* __restrict__ in, bf16* __restrict__ out, int n) {
  for (int i = blockIdx.x*256 + threadIdx.x; i < n; i += gridDim.x*256) out[i] = f2bf(in[i]);
}

// ---------------- row RMSNorm f32 -> bf16 ----------------
__global__ __launch_bounds__(256) void k_rms(const float* __restrict__ in, const float* __restrict__ w,
                                             bf16* __restrict__ out, int D) {
  int t = blockIdx.x;
  const float* row = in + (size_t)t * D;
  float ss = 0.f;
  for (int j = threadIdx.x; j < D/4; j += 256) {
    float4 v = ((const float4*)row)[j];
    ss += v.x*v.x + v.y*v.y + v.z*v.z + v.w*v.w;
  }
  ss = blockReduceSum(ss);
  float rs = rsqrtf(ss / (float)D + 1e-6f);
  for (int j = threadIdx.x; j < D/4; j += 256) {
    float4 v = ((const float4*)row)[j];
    float4 ww = ((const float4*)w)[j];
    union { short s[4]; uint2 u; } pk;
    pk.s[0] = f2b(v.x*rs*ww.x); pk.s[1] = f2b(v.y*rs*ww.y);
    pk.s[2] = f2b(v.z*rs*ww.z); pk.s[3] = f2b(v.w*rs*ww.w);
    ((uint2*)(out + (size_t)t*D))[j] = pk.u;
  }
}

// ---------------- rope tables: rows [0,T) from positions, rows [T,T+SC) pos=4s+3 ----------------
__global__ void k_rope_table(const int* __restrict__ positions, float* __restrict__ tabc, float* __restrict__ tabs) {
  int row = blockIdx.x * 8 + threadIdx.y;
  int i = threadIdx.x;   // 0..31
  if (row >= T + SC) return;
  float pos = (row < T) ? (float)positions[row] : (float)(4*(row - T) + 3);
  float freq = powf(160000.0f, -(float)i / 32.0f);
  float ang = pos * freq;
  tabc[(size_t)row*32 + i] = cosf(ang);
  tabs[(size_t)row*32 + i] = sinf(ang);
}

// ---------------- rope apply, vectorized: bf16 (T,HD) -> bf16, rope dims >= nope per head ----------------
__global__ __launch_bounds__(256) void k_rope8(const bf16* __restrict__ in, bf16* __restrict__ out,
                                               const float* __restrict__ tabc, const float* __restrict__ tabs,
                                               int HD, int Dn, int nope) {
  int t = blockIdx.x;
  int v8 = blockIdx.y*256 + threadIdx.x;
  int hd0 = v8*8;
  if (hd0 >= HD) return;
  int h = hd0 / Dn, d0 = hd0 - h*Dn;
  bf16x8 x = *(const bf16x8*)(in + (size_t)t*HD + hd0);
  union { short s[8]; bf16x8 v; } o;
  if (d0 < nope) { o.v = x; }
  else {
    int i0 = (d0 - nope) >> 1;   // multiple of 4
    float4 c4 = *(const float4*)(tabc + (size_t)t*32 + i0);
    float4 s4 = *(const float4*)(tabs + (size_t)t*32 + i0);
    float cA[4] = {c4.x,c4.y,c4.z,c4.w}, sA[4] = {s4.x,s4.y,s4.z,s4.w};
    #pragma unroll
    for (int pI = 0; pI < 4; pI++) {
      float x0 = b2f(x[2*pI]), x1 = b2f(x[2*pI+1]);
      o.s[2*pI]   = f2b(x0*cA[pI] - x1*sA[pI]);
      o.s[2*pI+1] = f2b(x0*sA[pI] + x1*cA[pI]);
    }
  }
  *(bf16x8*)(out + (size_t)t*HD + hd0) = o.v;
}

// ---------------- generic bf16 GEMM: C(MxN) = A(MxK_total) * BT(N x ldb)^T slice, m97-style ----------------
// lda/ldb: row strides of A and BT. K: the K-extent THIS launch accumulates.
// aZ/bZ: element offsets per blockIdx.z (split-K or grouped). cOffZ: flat C offset per z.
template<int BF16_OUT, int RES, int SWZ>
__global__ __launch_bounds__(256) void k_gemm(
    const bf16* __restrict__ A, int lda, long long aZ,
    const bf16* __restrict__ BT, int ldb, long long bZ,
    void* __restrict__ Cout, int ldc, long long cOffZ,
    const float* __restrict__ resid, int K)
{
  __shared__ bf16 sA[128*32];
  __shared__ bf16 sB[128*32];
  const int tid = threadIdx.x;
  const int w = tid >> 6, lane = tid & 63;
  const int wr = w >> 1, wc = w & 1;
  const int kid = lane >> 4, lr = lane & 15;
  int bn = blockIdx.x, bm = blockIdx.y, bz = blockIdx.z;
  if (SWZ) {   // bijective XCD swizzle (m204)
    int gx = gridDim.x, gy = gridDim.y;
    int nwg = gx*gy*gridDim.z;
    int lin = (bz*gy + bm)*gx + bn;
    int q = nwg >> 3, r = nwg & 7, x = lin & 7, s = lin >> 3;
    int m = (x < r) ? x*(q+1) + s : r*(q+1) + (x-r)*q + s;
    bn = m % gx; int tmp = m / gx; bm = tmp % gy; bz = tmp / gy;
  }
  const bf16* Ab = A + aZ*bz + (size_t)bm*128*lda;
  const bf16* Bb = BT + bZ*bz + (size_t)bn*128*ldb;
  f32x4 acc[4][4] = {};
  const int chb = w*128 + lane;
  for (int k0 = 0; k0 < K; k0 += 32) {
    #pragma unroll
    for (int i = 0; i < 2; i++) {
      int c = chb + i*64;
      gload16(Ab + (size_t)(c>>2)*lda + k0 + (c&3)*8, sA + (size_t)(w*128 + i*64)*8);
      gload16(Bb + (size_t)(c>>2)*ldb + k0 + (c&3)*8, sB + (size_t)(w*128 + i*64)*8);
    }
    __syncthreads();
    bf16x8 a[4], b[4];
    #pragma unroll
    for (int m = 0; m < 4; m++) a[m] = *(const bf16x8*)(sA + (wr*64 + m*16 + lr)*32 + kid*8);
    #pragma unroll
    for (int n = 0; n < 4; n++) b[n] = *(const bf16x8*)(sB + (wc*64 + n*16 + lr)*32 + kid*8);
    #pragma unroll
    for (int m = 0; m < 4; m++)
      #pragma unroll
      for (int n = 0; n < 4; n++)
        acc[m][n] = __builtin_amdgcn_mfma_f32_16x16x32_bf16(a[m], b[n], acc[m][n], 0, 0, 0);
    __syncthreads();
  }
  const int rb = bm*128 + wr*64 + kid*4;
  const int cb = bn*128 + wc*64 + lr;
  #pragma unroll
  for (int m = 0; m < 4; m++)
    #pragma unroll
    for (int n = 0; n < 4; n++)
      #pragma unroll
      for (int r = 0; r < 4; r++) {
        long long idx = cOffZ*bz + (long long)(rb + m*16 + r)*ldc + cb + n*16;
        float v = acc[m][n][r];
        if (RES) v += resid[idx];
        if (BF16_OUT) ((bf16*)Cout)[idx] = f2bf(v);
        else          ((float*)Cout)[idx] = v;
      }
}

// ---------------- split-K reduce: out = resid + sum_z partial[z], float4 ----------------
__global__ __launch_bounds__(256) void k_redN(const float* __restrict__ resid, const float* __restrict__ part,
                                              int nparts, long long stride, float* __restrict__ out, int n4) {
  int i = blockIdx.x*256 + threadIdx.x;
  if (i >= n4) return;
  float4 a = ((const float4*)resid)[i];
  for (int z = 0; z < nparts; z++) {
    float4 pv = ((const float4*)(part + stride*z))[i];
    a.x += pv.x; a.y += pv.y; a.z += pv.z; a.w += pv.w;
  }
  ((float4*)out)[i] = a;
}

// ---------------- indexer score GEMM + relu*iw reduction over 32 heads ----------------
__global__ __launch_bounds__(256) void k_iscore(
    const bf16* __restrict__ QI,   // (T*HI) x DI
    const bf16* __restrict__ KI,   // SC x DI
    const float* __restrict__ comb,// T x NCOMB (iw at col 1536)
    float* __restrict__ iscore)    // T x SC
{
  __shared__ bf16 sA[128*32];
  __shared__ bf16 sB[128*32];
  __shared__ float sc[512];
  const int tid = threadIdx.x;
  const int w = tid >> 6, lane = tid & 63;
  const int wr = w >> 1, wc = w & 1;
  const int kid = lane >> 4, lr = lane & 15;
  const int bm = blockIdx.y, bn = blockIdx.x;
  for (int i = tid; i < 512; i += 256) sc[i] = 0.f;
  const bf16* Ab = QI + (size_t)bm*128*DI;
  const bf16* Bb = KI + (size_t)bn*128*DI;
  f32x4 acc[4][4] = {};
  const int chb = w*128 + lane;
  for (int k0 = 0; k0 < DI; k0 += 32) {
    #pragma unroll
    for (int i = 0; i < 2; i++) {
      int c = chb + i*64;
      gload16(Ab + (size_t)(c>>2)*DI + k0 + (c&3)*8, sA + (size_t)(w*128 + i*64)*8);
      gload16(Bb + (size_t)(c>>2)*DI + k0 + (c&3)*8, sB + (size_t)(w*128 + i*64)*8);
    }
    __syncthreads();
    bf16x8 a[4], b[4];
    #pragma unroll
    for (int m = 0; m < 4; m++) a[m] = *(const bf16x8*)(sA + (wr*64 + m*16 + lr)*32 + kid*8);
    #pragma unroll
    for (int n = 0; n < 4; n++) b[n] = *(const bf16x8*)(sB + (wc*64 + n*16 + lr)*32 + kid*8);
    #pragma unroll
    for (int m = 0; m < 4; m++)
      #pragma unroll
      for (int n = 0; n < 4; n++)
        acc[m][n] = __builtin_amdgcn_mfma_f32_16x16x32_bf16(a[m], b[n], acc[m][n], 0, 0, 0);
    __syncthreads();
  }
  #pragma unroll
  for (int m = 0; m < 4; m++) {
    int rowl = wr*64 + m*16 + kid*4;
    #pragma unroll
    for (int r = 0; r < 4; r++) {
      int grow = bm*128 + rowl + r;
      int tt = grow >> 5, h = grow & 31;
      float wgt = comb[(size_t)tt*NCOMB + 1536 + h] * 0.08838834764831845f;  // * ISCALE
      #pragma unroll
      for (int n = 0; n < 4; n++) {
        float v = fmaxf(acc[m][n][r], 0.f) * wgt;
        atomicAdd(&sc[((rowl + r) >> 5)*128 + wc*64 + n*16 + lr], v);
      }
    }
  }
  __syncthreads();
  for (int i = tid; i < 512; i += 256)
    iscore[(size_t)(bm*4 + (i >> 7))*SC + bn*128 + (i & 127)] = sc[i];
}

// ---------------- compress combine (main kvc, d=256) ----------------
__global__ __launch_bounds__(256) void k_combine_c(
    const float* __restrict__ comb, const float* __restrict__ ape, const float* __restrict__ normw,
    const float* __restrict__ tabc, const float* __restrict__ tabs,
    bf16* __restrict__ kvc, bf16* __restrict__ kvcT)
{
  const int b = blockIdx.x, j = threadIdx.x;  // 256 threads
  float acc = 0.f;
  #pragma unroll
  for (int r = 0; r < 4; r++) {
    if (b > 0) {
      size_t tt = (size_t)(4*(b-1)+r) * NCOMB;
      acc += comb[tt + j] * sigm(comb[tt + 512 + j]) + ape[r*512 + j];
    }
    size_t t2 = (size_t)(4*b+r) * NCOMB;
    acc += comb[t2 + 256 + j] * sigm(comb[t2 + 512 + 256 + j]) + ape[r*512 + 256 + j];
  }
  acc *= 0.125f;
  float ss = blockReduceSum(acc*acc);
  float rs = rsqrtf(ss * (1.f/256.f) + 1e-6f);
  float nv = acc * rs * normw[j];
  __shared__ float sh[256];
  sh[j] = nv;
  __syncthreads();
  float outv;
  if (j < 192) outv = nv;
  else {
    int k = j - 192, i = k >> 1;
    float x0 = sh[192 + 2*i], x1 = sh[193 + 2*i];
    float c = tabc[(size_t)(T + b)*32 + i], sn = tabs[(size_t)(T + b)*32 + i];
    outv = (k & 1) ? (x0*sn + x1*c) : (x0*c - x1*sn);
  }
  kvc[(size_t)b*DH + j] = f2bf(outv);
  kvcT[(size_t)j*SC + b] = f2bf(outv);
}

// ---------------- compress combine (indexer ki, d=128) ----------------
__global__ __launch_bounds__(128) void k_combine_i(
    const float* __restrict__ comb, const float* __restrict__ ape, const float* __restrict__ normw,
    const float* __restrict__ tabc, const float* __restrict__ tabs,
    bf16* __restrict__ ki)
{
  const int b = blockIdx.x, j = threadIdx.x;  // 128 threads
  float acc = 0.f;
  #pragma unroll
  for (int r = 0; r < 4; r++) {
    if (b > 0) {
      size_t tt = (size_t)(4*(b-1)+r) * NCOMB;
      acc += comb[tt + 1024 + j] * sigm(comb[tt + 1280 + j]) + ape[r*256 + j];
    }
    size_t t2 = (size_t)(4*b+r) * NCOMB;
    acc += comb[t2 + 1024 + 128 + j] * sigm(comb[t2 + 1280 + 128 + j]) + ape[r*256 + 128 + j];
  }
  acc *= 0.125f;
  float ss = blockReduceSum(acc*acc);
  float rs = rsqrtf(ss * (1.f/128.f) + 1e-6f);
  float nv = acc * rs * normw[j];
  __shared__ float sh[128];
  sh[j] = nv;
  __syncthreads();
  float outv;
  if (j < 64) outv = nv;
  else {
    int k = j - 64, i = k >> 1;
    float x0 = sh[64 + 2*i], x1 = sh[64 + 2*i + 1];
    float c = tabc[(size_t)(T + b)*32 + i], sn = tabs[(size_t)(T + b)*32 + i];
    outv = (k & 1) ? (x0*sn + x1*c) : (x0*c - x1*sn);
  }
  ki[(size_t)b*DI + j] = f2bf(outv);
}

// ---------------- top-k threshold per row (bitonic sort 512 in LDS) ----------------
__global__ __launch_bounds__(256) void k_topk(const float* __restrict__ iscore,
                                              const int* __restrict__ positions,
                                              float* __restrict__ thresh) {
  const int t = blockIdx.x;
  int pos = positions[t];
  int nv = (pos + 1) >> 2; if (nv > SC) nv = SC;
  if (nv <= 256) { if (threadIdx.x == 0) thresh[t] = -3e38f; return; }
  __shared__ float arr[512];
  for (int i = threadIdx.x; i < 512; i += 256)
    arr[i] = (i < nv) ? iscore[(size_t)t*SC + i] : -1e30f;
  __syncthreads();
  for (int k = 2; k <= 512; k <<= 1)
    for (int j = k >> 1; j > 0; j >>= 1) {
      for (int idx = threadIdx.x; idx < 512; idx += 256) {
        int ixj = idx ^ j;
        if (ixj > idx) {
          bool up = ((idx & k) == 0);   // descending
          float a = arr[idx], b = arr[ixj];
          if (up ? (a < b) : (a > b)) { arr[idx] = b; arr[ixj] = a; }
        }
      }
      __syncthreads();
    }
  if (threadIdx.x == 0) thresh[t] = arr[255];
}

// ---------------- fused sparse attention: one block per token ----------------
__global__ __launch_bounds__(256) void k_attn(
    const bf16* __restrict__ q, const bf16* __restrict__ kvc, const bf16* __restrict__ kvcT,
    const float* __restrict__ iscore, const float* __restrict__ thresh,
    const int* __restrict__ positions, const float* __restrict__ sink,
    bf16* __restrict__ o)
{
  const int t = blockIdx.x;
  const int tid = threadIdx.x, w = tid >> 6, lane = tid & 63;
  const int kid = lane >> 4, lr = lane & 15;
  __shared__ bf16 pl[16*528];
  __shared__ float redm[4][16], reds[4][16];
  int pos = positions[t];
  int nv = (pos + 1) >> 2; if (nv > SC) nv = SC;
  float th = thresh[t];
  bf16x8 aq[8];
  const bf16* qrow = q + (size_t)t*(NH*DH) + lr*DH + kid*8;
  #pragma unroll
  for (int ks = 0; ks < 8; ks++) aq[ks] = *(const bf16x8*)(qrow + ks*32);
  f32x4 acc[8] = {};
  const int s0 = w*128;
  if (s0 < nv) {
    #pragma unroll
    for (int ks = 0; ks < 8; ks++) {
      bf16x8 bq[8];
      #pragma unroll
      for (int n = 0; n < 8; n++)
        bq[n] = *(const bf16x8*)(kvc + (size_t)(s0 + n*16 + lr)*DH + ks*32 + kid*8);
      #pragma unroll
      for (int n = 0; n < 8; n++)
        acc[n] = __builtin_amdgcn_mfma_f32_16x16x32_bf16(aq[ks], bq[n], acc[n], 0, 0, 0);
    }
  }
  float p[8][4];
  float mx[4] = {-3e38f, -3e38f, -3e38f, -3e38f};
  #pragma unroll
  for (int n = 0; n < 8; n++) {
    int s = s0 + n*16 + lr;
    bool keep = (s < nv) && (iscore[(size_t)t*SC + s] >= th);
    #pragma unroll
    for (int r = 0; r < 4; r++) {
      float v = keep ? acc[n][r] * 0.0625f : -1e30f;  // SCALE = DH^-0.5
      p[n][r] = v;
      mx[r] = fmaxf(mx[r], v);
    }
  }
  #pragma unroll
  for (int m2 = 1; m2 <= 8; m2 <<= 1)
    #pragma unroll
    for (int r = 0; r < 4; r++) mx[r] = fmaxf(mx[r], __shfl_xor(mx[r], m2, 64));
  if (lr == 0) {
    #pragma unroll
    for (int r = 0; r < 4; r++) redm[w][kid*4 + r] = mx[r];
  }
  __syncthreads();
  float M[4], sm[4];
  #pragma unroll
  for (int r = 0; r < 4; r++) {
    int h = kid*4 + r;
    float m = fmaxf(fmaxf(redm[0][h], redm[1][h]), fmaxf(redm[2][h], redm[3][h]));
    M[r] = fmaxf(m, sink[h]);
    sm[r] = 0.f;
  }
  #pragma unroll
  for (int n = 0; n < 8; n++)
    #pragma unroll
    for (int r = 0; r < 4; r++) {
      float e = __expf(p[n][r] - M[r]);
      p[n][r] = e;
      sm[r] += e;
    }
  #pragma unroll
  for (int m2 = 1; m2 <= 8; m2 <<= 1)
    #pragma unroll
    for (int r = 0; r < 4; r++) sm[r] += __shfl_xor(sm[r], m2, 64);
  if (lr == 0) {
    #pragma unroll
    for (int r = 0; r < 4; r++) reds[w][kid*4 + r] = sm[r];
  }
  __syncthreads();
  float inv[4];
  #pragma unroll
  for (int r = 0; r < 4; r++) {
    int h = kid*4 + r;
    float den = reds[0][h] + reds[1][h] + reds[2][h] + reds[3][h] + __expf(sink[h] - M[r]);
    inv[r] = 1.f / den;
  }
  #pragma unroll
  for (int n = 0; n < 8; n++)
    #pragma unroll
    for (int r = 0; r < 4; r++)
      pl[(kid*4 + r)*528 + s0 + n*16 + lr] = f2bf(p[n][r] * inv[r]);
  __syncthreads();
  int nch = (nv + 31) >> 5; if (nch > 16) nch = 16;
  f32x4 oacc[4] = {};
  for (int ks = 0; ks < nch; ks++) {
    bf16x8 ap = *(const bf16x8*)(pl + lr*528 + ks*32 + kid*8);
    #pragma unroll
    for (int n = 0; n < 4; n++) {
      bf16x8 bv = *(const bf16x8*)(kvcT + (size_t)(w*64 + n*16 + lr)*SC + ks*32 + kid*8);
      oacc[n] = __builtin_amdgcn_mfma_f32_16x16x32_bf16(ap, bv, oacc[n], 0, 0, 0);
    }
  }
  #pragma unroll
  for (int n = 0; n < 4; n++)
    #pragma unroll
    for (int r = 0; r < 4; r++)
      o[(size_t)t*(NH*DH) + (kid*4 + r)*DH + w*64 + n*16 + lr] = f2bf(oacc[n][r]);
}

// ---------------- SwiGLU activation ----------------
__global__ __launch_bounds__(256) void k_act(const bf16* __restrict__ gu, bf16* __restrict__ a) {
  size_t i = (size_t)blockIdx.x*256 + threadIdx.x;   // one 8-vector each
  size_t t = i >> 10;            // 1024 vectors per row (8192/8)
  size_t c = (i & 1023) * 8;
  bf16x8 g8 = *(const bf16x8*)(gu + t*16384 + c);
  bf16x8 u8 = *(const bf16x8*)(gu + t*16384 + 8192 + c);
  union { short s[8]; bf16x8 v; } outp;
  #pragma unroll
  for (int j = 0; j < 8; j++) {
    float g = b2f(g8[j]), u = b2f(u8[j]);
    outp.s[j] = f2b((g / (1.f + __expf(-g))) * u);
  }
  *(bf16x8*)(a + t*8192 + c) = outp.v;
}

extern "C" void kernel_launch(void* const* d_in, const int* in_sizes, int n_in,
                              void* d_out, int out_size, void* d_ws, size_t ws_size,
                              hipStream_t stream) {
  const float* hidden        = (const float*)d_in[0];
  const int*   positions     = (const int*)  d_in[1];
  const float* ln1_w         = (const float*)d_in[2];
  const float* ln2_w         = (const float*)d_in[3];
  const float* wq_a          = (const float*)d_in[4];
  const float* q_norm_w      = (const float*)d_in[5];
  const float* wq_b          = (const float*)d_in[6];
  const float* comp_wkv      = (const float*)d_in[7];
  const float* comp_wgate    = (const float*)d_in[8];
  const float* comp_ape      = (const float*)d_in[9];
  const float* comp_norm_w   = (const float*)d_in[10];
  const float* idx_wq_b      = (const float*)d_in[11];
  const float* idx_wproj     = (const float*)d_in[12];
  const float* icomp_wkv     = (const float*)d_in[13];
  const float* icomp_wgate   = (const float*)d_in[14];
  const float* icomp_ape     = (const float*)d_in[15];
  const float* icomp_norm_w  = (const float*)d_in[16];
  const float* attn_sink     = (const float*)d_in[17];
  const float* wo_a          = (const float*)d_in[18];
  const float* wo_b          = (const float*)d_in[19];
  const float* gate_up_w     = (const float*)d_in[20];
  const float* down_w        = (const float*)d_in[21];
  float* outp = (float*)d_out;

  char* p = (char*)d_ws;
  auto take = [&](size_t n) { char* r = p; p += (n + 255) & ~(size_t)255; return r; };
  // ---- persistent bf16 weights ----
  bf16* wq_aT    = (bf16*)take((size_t)QL*DIM*2);        // 6.3 MB   (also partial2 base later)
  bf16* wq_bT    = (bf16*)take((size_t)4096*QL*2);       // 12.6 MB
  bf16* idx_wq_bT= (bf16*)take((size_t)4096*QL*2);       // 12.6 MB
  bf16* WcombT   = (bf16*)take((size_t)NCOMB*DIM*2);     // 6.8 MB
  bf16* wo_a_bf  = (bf16*)take((size_t)4*512*1024*2);    // 4.2 MB
  bf16* wo_bT    = (bf16*)take((size_t)DIM*DIM*2);       // 8.4 MB
  bf16* gate_upT = (bf16*)take((size_t)2*II*DIM*2);      // 67.1 MB  (also partial4 later)
  bf16* downT    = (bf16*)take((size_t)DIM*II*2);        // 33.6 MB
  bf16* x_bf     = (bf16*)take((size_t)T*DIM*2);         // 8.4 MB
  // ---- R1 (64 MB): {qtmp_bf 16 | q_bf 16 | qi_bf 16 | -} -> {o_bf@0, oa_bf@32M} -> gu (full)
  char* R1 = take((size_t)T*16384*2);
  bf16*  qtmp_bf = (bf16*)R1;
  bf16*  q_bf    = (bf16*)(R1 + (size_t)16777216);
  bf16*  qi_bf   = (bf16*)(R1 + (size_t)33554432);
  bf16*  o_bf    = (bf16*)R1;
  bf16*  oa_bf   = (bf16*)(R1 + (size_t)33554432);
  bf16*  gu      = (bf16*)R1;
  // ---- R2 (36.7 MB): {qx 12.6 | qr 6.3 | comb 13.6 | iscore 4.2} -> x2 over comb -> a_bf over all
  char* R2 = take((size_t)36700160);
  float* qx     = (float*)R2;
  bf16*  qr     = (bf16*)(R2 + (size_t)12582912);
  float* comb   = (float*)(R2 + (size_t)18874368);
  float* iscore = (float*)(R2 + (size_t)32505856);
  bf16*  x2     = (bf16*)(R2 + (size_t)18874368);
  bf16*  a_bf   = (bf16*)R2;
  // ---- persistent small ----
  float* hbuf = (float*)take((size_t)T*DIM*4);           // 16.8 MB
  bf16* kvc   = (bf16*)take((size_t)SC*DH*2);
  bf16* kvcT  = (bf16*)take((size_t)DH*SC*2);
  bf16* ki    = (bf16*)take((size_t)SC*DI*2);
  float* tabc = (float*)take((size_t)(T+SC)*32*4);
  float* tabs = (float*)take((size_t)(T+SC)*32*4);
  float* thr  = (float*)take((size_t)T*4);
  // split-K partial overlays (regions dead at time of use; rewritten each call)
  float* partial4 = (float*)gate_upT;   // 4 x T*DIM f32 = 67.1 MB over gate_upT
  float* partial2 = (float*)wq_aT;      // 2 x T*DIM f32 = 33.6 MB over wq_aT..WcombT

  // weight convert/transpose (f32 row-major -> bf16 transposed / B^T form)
  k_transpose64<<<dim3(QL/64, DIM/64), 256, 0, stream>>>(wq_a, wq_aT, DIM, QL);
  k_transpose64<<<dim3(4096/64, QL/64), 256, 0, stream>>>(wq_b, wq_bT, QL, 4096);
  k_transpose64<<<dim3(4096/64, QL/64), 256, 0, stream>>>(idx_wq_b, idx_wq_bT, QL, 4096);
  k_transpose64<<<dim3(512/64, DIM/64), 256, 0, stream>>>(comp_wkv,   WcombT + (size_t)0*DIM,    DIM, 512);
  k_transpose64<<<dim3(512/64, DIM/64), 256, 0, stream>>>(comp_wgate, WcombT + (size_t)512*DIM,  DIM, 512);
  k_transpose64<<<dim3(256/64, DIM/64), 256, 0, stream>>>(icomp_wkv,  WcombT + (size_t)1024*DIM, DIM, 256);
  k_transpose64<<<dim3(256/64, DIM/64), 256, 0, stream>>>(icomp_wgate,WcombT + (size_t)1280*DIM, DIM, 256);
  k_transpose32<<<dim3(1, DIM/32), dim3(32,8), 0, stream>>>(idx_wproj, WcombT + (size_t)1536*DIM, DIM, 32);
  k_transpose64<<<dim3(DIM/64, DIM/64), 256, 0, stream>>>(wo_b, wo_bT, DIM, DIM);
  k_transpose64<<<dim3(16384/64, DIM/64), 256, 0, stream>>>(gate_up_w, gate_upT, DIM, 16384);
  k_transpose64<<<dim3(DIM/64, II/64), 256, 0, stream>>>(down_w, downT, II, DIM);
  k_convert<<<2048, 256, 0, stream>>>(wo_a, wo_a_bf, 4*512*1024);
  k_rope_table<<<(T + SC + 7)/8, dim3(32,8), 0, stream>>>(positions, tabc, tabs);

  // x = rms(hidden, ln1)
  k_rms<<<T, 256, 0, stream>>>(hidden, ln1_w, x_bf, DIM);
  // qx = x @ wq_a ; qr = rms(qx, q_norm_w)
  k_gemm<0,0,1><<<dim3(QL/128, T/128), 256, 0, stream>>>(x_bf, DIM, 0, wq_aT, DIM, 0, qx, QL, 0, nullptr, DIM);
  k_rms<<<T, 256, 0, stream>>>(qx, q_norm_w, qr, QL);
  // q = rope(qr @ wq_b)
  k_gemm<1,0,1><<<dim3(4096/128, T/128), 256, 0, stream>>>(qr, QL, 0, wq_bT, QL, 0, qtmp_bf, 4096, 0, nullptr, QL);
  k_rope8<<<dim3(T, 2), 256, 0, stream>>>(qtmp_bf, q_bf, tabc, tabs, 4096, DH, 192);
  // qi = rope(qr @ idx_wq_b)
  k_gemm<1,0,1><<<dim3(4096/128, T/128), 256, 0, stream>>>(qr, QL, 0, idx_wq_bT, QL, 0, qtmp_bf, 4096, 0, nullptr, QL);
  k_rope8<<<dim3(T, 2), 256, 0, stream>>>(qtmp_bf, qi_bf, tabc, tabs, 4096, DI, 64);
  // comb = x @ [comp_wkv|comp_wgate|icomp_wkv|icomp_wgate|idx_proj]
  k_gemm<0,0,1><<<dim3(NCOMB/128, T/128), 256, 0, stream>>>(x_bf, DIM, 0, WcombT, DIM, 0, comb, NCOMB, 0, nullptr, DIM);
  k_combine_c<<<SC, 256, 0, stream>>>(comb, comp_ape, comp_norm_w, tabc, tabs, kvc, kvcT);
  k_combine_i<<<SC, 128, 0, stream>>>(comb, icomp_ape, icomp_norm_w, tabc, tabs, ki);
  // indexer scores + top-k threshold
  k_iscore<<<dim3(4, 512), 256, 0, stream>>>(qi_bf, ki, comb, iscore);
  k_topk<<<T, 256, 0, stream>>>(iscore, positions, thr);
  // sparse attention
  k_attn<<<T, 256, 0, stream>>>(q_bf, kvc, kvcT, iscore, thr, positions, attn_sink, o_bf);
  // oa = grouped o @ wo_a
  k_gemm<1,0,1><<<dim3(4, T/128, 4), 256, 0, stream>>>(o_bf, NH*DH, 1024, wo_a_bf, 1024, (long long)512*1024,
                                                       oa_bf, DIM, 512, nullptr, 1024);
  // h = hidden + oa @ wo_b   (split-K=2: partials + reduce)  [ldb = 2048 = true row stride]
  k_gemm<0,0,1><<<dim3(DIM/128, T/128, 2), 256, 0, stream>>>(oa_bf, DIM, 1024, wo_bT, DIM, 1024,
                                                             partial2, DIM, (long long)T*DIM, nullptr, 1024);
  k_redN<<<(T*DIM/4 + 255)/256, 256, 0, stream>>>(hidden, partial2, 2, (long long)T*DIM, hbuf, T*DIM/4);
  k_rms<<<T, 256, 0, stream>>>(hbuf, ln2_w, x2, DIM);
  // MLP
  k_gemm<1,0,1><<<dim3(16384/128, T/128), 256, 0, stream>>>(x2, DIM, 0, gate_upT, DIM, 0, gu, 16384, 0, nullptr, DIM);
  k_act<<<(int)((size_t)T*II/8/256), 256, 0, stream>>>(gu, a_bf);
  // out = hbuf + a @ down   (split-K=4: partials + reduce)  [ldb = 8192 = true row stride]
  k_gemm<0,0,1><<<dim3(DIM/128, T/128, 4), 256, 0, stream>>>(a_bf, II, 2048, downT, II, 2048,
                                                             partial4, DIM, (long long)T*DIM, nullptr, 2048);
  k_redN<<<(T*DIM/4 + 255)/256, 256, 0, stream>>>(hbuf, partial4, 4, (long long)T*DIM, outp, T*DIM/4);
}